// Round 6
// baseline (219.906 us; speedup 1.0000x reference)
//
#include <hip/hip_runtime.h>
#include <hip/hip_bf16.h>

#define BB 4
#define TT 4096
#define HH 2048
#define NSLOT 64
#define KD 256
#define VD 256
#define BT (BB*TT)
#define NEGV (-1e9f)
#define EPSV 1e-5f

typedef __attribute__((ext_vector_type(8))) short short8;
typedef __attribute__((ext_vector_type(4))) float floatx4;

union B8 { short8 v; unsigned short u[8]; };

__device__ inline unsigned short f2bf(float x) {
  unsigned u = __float_as_uint(x);
  return (unsigned short)((u + 0x7FFFu + ((u >> 16) & 1u)) >> 16);
}
__device__ inline float bf2f(unsigned short h) {
  return __uint_as_float(((unsigned)h) << 16);
}
// 8 fp32 -> hi/lo bf16 (hi = RNE(x), lo = RNE(x - hi))
__device__ inline void cvt8(const float4 a, const float4 b, B8& h, B8& l) {
  const float f[8] = {a.x, a.y, a.z, a.w, b.x, b.y, b.z, b.w};
#pragma unroll
  for (int j = 0; j < 8; ++j) {
    unsigned short hh = f2bf(f[j]);
    h.u[j] = hh;
    l.u[j] = f2bf(f[j] - bf2f(hh));
  }
}

// ---------------- mask dtype detection + conversion (16 blocks) -------------
__global__ void mask_convert_kernel(const void* valid_raw, const void* hist_raw,
                                    int* valid_int, int* hist_int) {
  __shared__ int mode_s;
  const int tid = threadIdx.x;
  if (tid == 0) {
    const unsigned int* w = (const unsigned int*)valid_raw;
    int all01 = 1, anyfloat = 0;
    for (int i = 0; i < 64; ++i) {
      unsigned int x = w[i];
      if (x != 0u && x != 1u) all01 = 0;
      if (x == 0x3F800000u) anyfloat = 1;
    }
    mode_s = all01 ? 0 : (anyfloat ? 1 : 2);
  }
  __syncthreads();
  const int mode = mode_s;
  if (blockIdx.x == 0) {
    const int* vi = (const int*)valid_raw;
    const float* vf = (const float*)valid_raw;
    const unsigned char* vb = (const unsigned char*)valid_raw;
    for (int i = tid; i < BB * NSLOT; i += blockDim.x)
      valid_int[i] = (mode == 0) ? (vi[i] != 0)
                   : (mode == 1) ? (vf[i] != 0.0f)
                                 : (vb[i] != 0);
  }
  {
    const int* vi = (const int*)hist_raw;
    const float* vf = (const float*)hist_raw;
    const unsigned char* vb = (const unsigned char*)hist_raw;
    const int base = blockIdx.x * 1024;
    for (int i = tid; i < 1024; i += blockDim.x) {
      const int g = base + i;
      hist_int[g] = (mode == 0) ? (vi[g] != 0)
                  : (mode == 1) ? (vf[g] != 0.0f)
                                : (vb[g] != 0);
    }
  }
}

// ---------------- PK[b,n,h] = sum_k keys[b,n,k] * Wq[k,h]  (fp32) -----------
__global__ __launch_bounds__(256) void pk_kernel(const float* __restrict__ keys,
                                                 const float* __restrict__ Wq,
                                                 float* __restrict__ PK) {
  const int b = blockIdx.x >> 5;
  const int h0 = (blockIdx.x & 31) * 64;
  __shared__ float ks[64][260];
  const int tid = threadIdx.x;
  const float* kb = keys + (size_t)b * 64 * 256;
  for (int i = tid; i < 64 * 64; i += 256) {
    const int n = i >> 6, k4 = (i & 63) * 4;
    *(float4*)&ks[n][k4] = *(const float4*)&kb[n * 256 + k4];
  }
  __syncthreads();
  const int h = h0 + (tid & 63);
  const int ng = tid >> 6;
  float acc[16] = {};
  for (int k = 0; k < 256; ++k) {
    const float wq = Wq[(size_t)k * HH + h];
#pragma unroll
    for (int i = 0; i < 16; ++i) acc[i] += ks[i * 4 + ng][k] * wq;
  }
#pragma unroll
  for (int i = 0; i < 16; ++i)
    PK[((size_t)b * 64 + i * 4 + ng) * HH + h] = acc[i];
}

// -------- PK -> hi/lo bf16 MFMA-fragment layout -----------------------------
__global__ __launch_bounds__(64) void pkfrag_kernel(const float* __restrict__ PK,
                                                    unsigned short* __restrict__ PKh,
                                                    unsigned short* __restrict__ PKl) {
  const int b = blockIdx.x >> 6, kc = blockIdx.x & 63;
  const int lane = threadIdx.x, fr = lane & 15, hi4 = lane >> 4;
#pragma unroll
  for (int nt = 0; nt < 4; ++nt) {
    const float* src = &PK[((size_t)b * 64 + nt * 16 + fr) * HH + kc * 32 + hi4 * 8];
    const float4 a = *(const float4*)src;
    const float4 c = *(const float4*)(src + 4);
    B8 h, l;
    cvt8(a, c, h, l);
    const size_t off = (((size_t)(b * 64 + kc) * 4 + nt) * 64 + lane) * 8;
    *(short8*)&PKh[off] = h.v;
    *(short8*)&PKl[off] = l.v;
  }
}

// -------- V^T bf16 fragment layout ------------------------------------------
__global__ __launch_bounds__(64) void vtfrag_kernel(const float* __restrict__ vals,
                                                    unsigned short* __restrict__ VtF) {
  const int b = blockIdx.x >> 5, vt = (blockIdx.x >> 1) & 15, kc = blockIdx.x & 1;
  const int lane = threadIdx.x, fr = lane & 15, hi4 = lane >> 4;
  B8 t;
#pragma unroll
  for (int j = 0; j < 8; ++j) {
    const int n = kc * 32 + hi4 * 8 + j;
    t.u[j] = f2bf(vals[((size_t)b * 64 + n) * 256 + vt * 16 + fr]);
  }
  *(short8*)&VtF[(((size_t)b * 16 + vt) * 2 + kc) * 512 + lane * 8] = t.v;
}

// -------- Wo bf16 fragment layout -------------------------------------------
__global__ __launch_bounds__(64) void wofrag_kernel(const float* __restrict__ Wo,
                                                    unsigned short* __restrict__ WoF) {
  const int lane = threadIdx.x, fr = lane & 15, hi4 = lane >> 4;
  const int nt = blockIdx.x >> 3, kk = blockIdx.x & 7;
  const float* src = &Wo[(size_t)(nt * 16 + fr) * 256 + kk * 32 + hi4 * 8];
  const float4 a = *(const float4*)src;
  const float4 b2 = *(const float4*)(src + 4);
  B8 t;
  t.u[0] = f2bf(a.x); t.u[1] = f2bf(a.y); t.u[2] = f2bf(a.z); t.u[3] = f2bf(a.w);
  t.u[4] = f2bf(b2.x); t.u[5] = f2bf(b2.y); t.u[6] = f2bf(b2.z); t.u[7] = f2bf(b2.w);
  *(short8*)&WoF[(size_t)blockIdx.x * 512 + lane * 8] = t.v;
}

// -------- attn v6: barrier-free K-split, in-reg cvt, 4-deep prefetch --------
// block = 256 thr (4 waves), 16 tokens; wave w owns K cols w*512..+512.
// grid 1024 (4 blocks/CU)
__global__ __launch_bounds__(256, 4) void attn_kernel(
    const float* __restrict__ hs,          // [BT,2048]
    const unsigned short* __restrict__ PKh,
    const unsigned short* __restrict__ PKl,
    const unsigned short* __restrict__ VtF,
    const int* __restrict__ valid,
    const int* __restrict__ hist,
    __hip_bfloat16* __restrict__ retrB) {  // [BT,256]
  const int t0 = blockIdx.x * 16;
  const int b = blockIdx.x >> 8;           // 256 blocks per batch
  const int tid = threadIdx.x;
  const int w = tid >> 6, lane = tid & 63;
  const int fr = lane & 15, hi4 = lane >> 4;

  __shared__ float S[4][16][68];
  __shared__ __align__(16) unsigned short P[16][88];

  floatx4 acc[4];
#pragma unroll
  for (int nt = 0; nt < 4; ++nt) acc[nt] = (floatx4){0.f, 0.f, 0.f, 0.f};

  const float* arow = &hs[(size_t)(t0 + fr) * HH + hi4 * 8];
  const int kc0 = w * 16;

  // 4-deep A prefetch ring (static-indexed via unroll-by-4)
  float4 va0[4], va1[4];
#pragma unroll
  for (int p = 0; p < 4; ++p) {
    va0[p] = *(const float4*)(arow + (kc0 + p) * 32);
    va1[p] = *(const float4*)(arow + (kc0 + p) * 32 + 4);
  }

#pragma unroll 4
  for (int c = 0; c < 16; ++c) {
    const int cc = c & 3;
    B8 ah, al;
    cvt8(va0[cc], va1[cc], ah, al);
    if (c < 12) {
      va0[cc] = *(const float4*)(arow + (kc0 + c + 4) * 32);
      va1[cc] = *(const float4*)(arow + (kc0 + c + 4) * 32 + 4);
    }
    const size_t pkbase = ((size_t)(b * 64 + kc0 + c) * 4) * 512 + lane * 8;
#pragma unroll
    for (int nt = 0; nt < 4; ++nt) {
      const short8 bh = *(const short8*)&PKh[pkbase + nt * 512];
      const short8 bl = *(const short8*)&PKl[pkbase + nt * 512];
      acc[nt] = __builtin_amdgcn_mfma_f32_16x16x32_bf16(ah.v, bh, acc[nt], 0, 0, 0);
      acc[nt] = __builtin_amdgcn_mfma_f32_16x16x32_bf16(al.v, bh, acc[nt], 0, 0, 0);
      acc[nt] = __builtin_amdgcn_mfma_f32_16x16x32_bf16(ah.v, bl, acc[nt], 0, 0, 0);
    }
  }

  // partial scores: token = hi4*4+rr, slot = nt*16+fr
#pragma unroll
  for (int nt = 0; nt < 4; ++nt)
#pragma unroll
    for (int rr = 0; rr < 4; ++rr)
      S[w][hi4 * 4 + rr][nt * 16 + fr] = acc[nt][rr];
  __syncthreads();

  // softmax: wave w -> tokens w*4..w*4+3; lane = slot
  const int vmy = valid[b * 64 + lane];
  const unsigned long long bal = __ballot(vmy != 0);
  const float any = (bal != 0ull) ? 1.0f : 0.0f;
#pragma unroll
  for (int i = 0; i < 4; ++i) {
    const int tt = w * 4 + i;
    float s = S[0][tt][lane] + S[1][tt][lane] + S[2][tt][lane] + S[3][tt][lane];
    s = vmy ? s : NEGV;
    float m = s;
#pragma unroll
    for (int o = 32; o; o >>= 1) m = fmaxf(m, __shfl_xor(m, o));
    const float e = __expf(s - m);
    float sum = e;
#pragma unroll
    for (int o = 32; o; o >>= 1) sum += __shfl_xor(sum, o);
    P[tt][lane] = f2bf(e / sum * any);
  }
  __syncthreads();

  // PV: wave w -> v-tiles w*4..w*4+3 (cols w*64..+63)
  short8 pa[2];
#pragma unroll
  for (int ks = 0; ks < 2; ++ks)
    pa[ks] = *(const short8*)&P[fr][ks * 32 + hi4 * 8];
  floatx4 acc2[4];
#pragma unroll
  for (int j = 0; j < 4; ++j) acc2[j] = (floatx4){0.f, 0.f, 0.f, 0.f};
  const size_t vbase = (size_t)(b * 16) * 2 * 512 + lane * 8;
#pragma unroll
  for (int j = 0; j < 4; ++j) {
    const int vt = w * 4 + j;
    const short8 v0 = *(const short8*)&VtF[vbase + (size_t)(vt * 2 + 0) * 512];
    const short8 v1 = *(const short8*)&VtF[vbase + (size_t)(vt * 2 + 1) * 512];
    acc2[j] = __builtin_amdgcn_mfma_f32_16x16x32_bf16(pa[0], v0, acc2[j], 0, 0, 0);
    acc2[j] = __builtin_amdgcn_mfma_f32_16x16x32_bf16(pa[1], v1, acc2[j], 0, 0, 0);
  }
#pragma unroll
  for (int rr = 0; rr < 4; ++rr) {
    const int tok = t0 + hi4 * 4 + rr;
    const float allowed = hist[tok] ? 0.0f : 1.0f;
#pragma unroll
    for (int j = 0; j < 4; ++j)
      retrB[(size_t)tok * 256 + (w * 4 + j) * 16 + fr] =
          __float2bfloat16(acc2[j][rr] * allowed);
  }
}

// -------- GEMM2 + residual + LayerNorm fused, 32 tokens/block ---------------
// 512 thr (8 waves x 256 cols), grid 512; full-unroll kk with B double-buffer
__global__ __launch_bounds__(512, 2) void gemm2_ln_kernel(
    const __hip_bfloat16* __restrict__ A,   // retrB [BT,256]
    const unsigned short* __restrict__ WoF, // frag layout
    const float* __restrict__ RES,          // hs
    const float* __restrict__ gamma,
    const float* __restrict__ beta,
    float* __restrict__ out) {
  const int m0 = blockIdx.x * 32;
  const int tid = threadIdx.x;
  const int wid = tid >> 6, lane = tid & 63;
  const int fr = lane & 15, hi4 = lane >> 4;

  __shared__ __align__(16) unsigned short As[32][264];
  __shared__ float part[32][8][2];
  __shared__ float stats[32][2];

#pragma unroll
  for (int it = 0; it < 2; ++it) {
    const int g = tid + it * 512;
    const int r = g >> 5, c8 = g & 31;
    *(short8*)&As[r][c8 * 8] =
        *(const short8*)&A[(size_t)(m0 + r) * 256 + c8 * 8];
  }

  floatx4 acc[2][16];
#pragma unroll
  for (int mf = 0; mf < 2; ++mf)
#pragma unroll
    for (int j = 0; j < 16; ++j) acc[mf][j] = (floatx4){0.f, 0.f, 0.f, 0.f};

  const unsigned short* wbase = &WoF[(size_t)(wid * 16) * 8 * 512 + lane * 8];
  short8 bcur[16];
#pragma unroll
  for (int j = 0; j < 16; ++j)
    bcur[j] = *(const short8*)&wbase[(size_t)j * 4096];
  __syncthreads();

#pragma unroll
  for (int kk = 0; kk < 8; ++kk) {
    short8 bn0[8], bn1[8];
    if (kk < 7) {
#pragma unroll
      for (int j = 0; j < 8; ++j)
        bn0[j] = *(const short8*)&wbase[(size_t)j * 4096 + (kk + 1) * 512];
    }
    const short8 af0 = *(const short8*)&As[fr][kk * 32 + hi4 * 8];
    const short8 af1 = *(const short8*)&As[16 + fr][kk * 32 + hi4 * 8];
#pragma unroll
    for (int j = 0; j < 8; ++j) {
      acc[0][j] = __builtin_amdgcn_mfma_f32_16x16x32_bf16(af0, bcur[j], acc[0][j], 0, 0, 0);
      acc[1][j] = __builtin_amdgcn_mfma_f32_16x16x32_bf16(af1, bcur[j], acc[1][j], 0, 0, 0);
    }
    if (kk < 7) {
#pragma unroll
      for (int j = 0; j < 8; ++j)
        bn1[j] = *(const short8*)&wbase[(size_t)(j + 8) * 4096 + (kk + 1) * 512];
    }
#pragma unroll
    for (int j = 8; j < 16; ++j) {
      acc[0][j] = __builtin_amdgcn_mfma_f32_16x16x32_bf16(af0, bcur[j], acc[0][j], 0, 0, 0);
      acc[1][j] = __builtin_amdgcn_mfma_f32_16x16x32_bf16(af1, bcur[j], acc[1][j], 0, 0, 0);
    }
    if (kk < 7) {
#pragma unroll
      for (int j = 0; j < 8; ++j) { bcur[j] = bn0[j]; bcur[j + 8] = bn1[j]; }
    }
  }

  // residual + per-row partial stats (token = mf*16 + hi4*4+rr)
  float msum[2][4] = {}, msq[2][4] = {};
#pragma unroll
  for (int mf = 0; mf < 2; ++mf)
#pragma unroll
    for (int j = 0; j < 16; ++j)
#pragma unroll
      for (int rr = 0; rr < 4; ++rr) {
        const int row = mf * 16 + hi4 * 4 + rr;
        const int col = wid * 256 + j * 16 + fr;
        const float x = acc[mf][j][rr] + RES[(size_t)(m0 + row) * HH + col];
        acc[mf][j][rr] = x;
        msum[mf][rr] += x;
        msq[mf][rr] += x * x;
      }
#pragma unroll
  for (int mf = 0; mf < 2; ++mf)
#pragma unroll
    for (int rr = 0; rr < 4; ++rr) {
      float s = msum[mf][rr], q = msq[mf][rr];
#pragma unroll
      for (int o = 8; o; o >>= 1) {
        s += __shfl_xor(s, o);
        q += __shfl_xor(q, o);
      }
      if (fr == 0) {
        part[mf * 16 + hi4 * 4 + rr][wid][0] = s;
        part[mf * 16 + hi4 * 4 + rr][wid][1] = q;
      }
    }
  __syncthreads();
  if (tid < 32) {
    float Sm = 0.f, Q = 0.f;
#pragma unroll
    for (int ww = 0; ww < 8; ++ww) {
      Sm += part[tid][ww][0];
      Q += part[tid][ww][1];
    }
    const float mu = Sm * (1.0f / HH);
    const float var = Q * (1.0f / HH) - mu * mu;
    stats[tid][0] = mu;
    stats[tid][1] = rsqrtf(var + EPSV);
  }
  __syncthreads();

#pragma unroll
  for (int mf = 0; mf < 2; ++mf)
#pragma unroll
    for (int j = 0; j < 16; ++j) {
      const int col = wid * 256 + j * 16 + fr;
      const float g = gamma[col], bt = beta[col];
#pragma unroll
      for (int rr = 0; rr < 4; ++rr) {
        const int row = mf * 16 + hi4 * 4 + rr;
        out[(size_t)(m0 + row) * HH + col] =
            (acc[mf][j][rr] - stats[row][0]) * stats[row][1] * g + bt;
      }
    }
}

extern "C" void kernel_launch(void* const* d_in, const int* in_sizes, int n_in,
                              void* d_out, int out_size, void* d_ws, size_t ws_size,
                              hipStream_t stream) {
  const float* hs    = (const float*)d_in[0];
  const float* keys  = (const float*)d_in[1];
  const float* vals  = (const float*)d_in[2];
  const float* Wq    = (const float*)d_in[3];
  const float* Wo    = (const float*)d_in[4];
  const float* gamma = (const float*)d_in[5];
  const float* beta  = (const float*)d_in[6];
  const void* valid_raw = d_in[7];
  const void* hist_raw  = d_in[8];
  float* out = (float*)d_out;

  char* w = (char*)d_ws;
  float* PK            = (float*)w;                         // 2 MB
  unsigned short* PKh  = (unsigned short*)(w + (2u << 20)); // 1 MB
  unsigned short* PKl  = (unsigned short*)(w + (3u << 20)); // 1 MB
  unsigned short* VtF  = (unsigned short*)(w + (4u << 20)); // 256 KB
  unsigned short* WoF  = (unsigned short*)(w + (5u << 20)); // 1 MB
  __hip_bfloat16* retrB = (__hip_bfloat16*)(w + (6u << 20)); // 8 MB
  int* valid_int = (int*)(w + (15u << 20));
  int* hist_int  = valid_int + BB * NSLOT;

  mask_convert_kernel<<<dim3(16), dim3(256), 0, stream>>>(valid_raw, hist_raw,
                                                          valid_int, hist_int);
  pk_kernel<<<dim3(128), dim3(256), 0, stream>>>(keys, Wq, PK);
  pkfrag_kernel<<<dim3(256), dim3(64), 0, stream>>>(PK, PKh, PKl);
  vtfrag_kernel<<<dim3(128), dim3(64), 0, stream>>>(vals, VtF);
  wofrag_kernel<<<dim3(1024), dim3(64), 0, stream>>>(Wo, WoF);
  attn_kernel<<<dim3(BT / 16), dim3(256), 0, stream>>>(
      hs, PKh, PKl, VtF, valid_int, hist_int, retrB);
  gemm2_ln_kernel<<<dim3(BT / 32), dim3(512), 0, stream>>>(
      retrB, WoF, hs, gamma, beta, out);
}